// Round 8
// baseline (222.407 us; speedup 1.0000x reference)
//
#include <hip/hip_runtime.h>
#include <hip/hip_bf16.h>

// NT-Xent, BATCH=4096, N=8192, D=512, TEMP=0.1 — MX-fp8 (e4m3, unit scales)
// mfma_scale_f32_32x32x64_f8f6f4, 128x256 tile, BK=64, 512 thr, 48 KB LDS,
// 2 blocks/CU (r7 cross-block latency-hiding structure).
// loss = mean_i [ logsumexp_{j!=i} sim[i,j] - sim[i,partner(i)] ]
// acc  = mean_i [ sim[i,partner(i)] >= max_{j!=i,partner} sim[i,j] ]
// sim = (msg_n . img_n^T)/TEMP, 10x folded into msg side before fp8 cast.

#define NROWS 8192
#define BATCHD 4096
#define DIM 512
#define BM 128
#define BN 256
#define BK 64
#define NSTEP (DIM / BK)   // 8 K-steps
#define SHIFT 10.0f

typedef int i32x8 __attribute__((ext_vector_type(8)));
typedef float f32x16 __attribute__((ext_vector_type(16)));

#define GLDS(g, l)                                                             \
    __builtin_amdgcn_global_load_lds(                                          \
        (const __attribute__((address_space(1))) void*)(g),                    \
        (__attribute__((address_space(3))) void*)(l), 16, 0, 0)

__device__ __forceinline__ unsigned f2u_ord(float f) {
    unsigned u = __float_as_uint(f);
    return (u & 0x80000000u) ? ~u : (u | 0x80000000u);
}
__device__ __forceinline__ float u2f_ord(unsigned e) {
    return (e & 0x80000000u) ? __uint_as_float(e & 0x7fffffffu) : __uint_as_float(~e);
}

// blocks 0..NROWS-1: msg (x10); NROWS..2*NROWS-1: img (x1).
// First 128 blocks also zero rowsum/rowmax/accum.
__global__ __launch_bounds__(64) void normalize_fp8_both(const float* __restrict__ msg,
                                                         const float* __restrict__ img,
                                                         unsigned char* __restrict__ mnb,
                                                         unsigned char* __restrict__ imb,
                                                         float* __restrict__ rowsum,
                                                         unsigned* __restrict__ rowmax,
                                                         float* __restrict__ accum) {
    if (blockIdx.x < 128) {
        const int i = blockIdx.x * 64 + threadIdx.x;
        rowsum[i] = 0.f;
        rowmax[i] = 0u;  // encodes "most negative"
        if (i < 2) accum[i] = 0.f;
    }
    int row = blockIdx.x;
    const float* in;
    unsigned char* out;
    float scale;
    if (row < NROWS) { in = msg; out = mnb; scale = 10.0f; }
    else { row -= NROWS; in = img; out = imb; scale = 1.0f; }
    const int lane = threadIdx.x;
    const float* src = in + (size_t)row * DIM + lane * 8;
    float4 v0 = *(const float4*)(src);
    float4 v1 = *(const float4*)(src + 4);
    float ss = v0.x*v0.x + v0.y*v0.y + v0.z*v0.z + v0.w*v0.w
             + v1.x*v1.x + v1.y*v1.y + v1.z*v1.z + v1.w*v1.w;
    #pragma unroll
    for (int off = 1; off < 64; off <<= 1) ss += __shfl_xor(ss, off);
    const float inv = scale / fmaxf(sqrtf(ss), 1e-8f);
    // pack 8 f32 -> 8 fp8 e4m3 bytes (v_cvt_pk_fp8_f32: RNE, OCP e4m3fn)
    int w0 = __builtin_amdgcn_cvt_pk_fp8_f32(v0.x * inv, v0.y * inv, 0, false);
    w0 = __builtin_amdgcn_cvt_pk_fp8_f32(v0.z * inv, v0.w * inv, w0, true);
    int w1 = __builtin_amdgcn_cvt_pk_fp8_f32(v1.x * inv, v1.y * inv, 0, false);
    w1 = __builtin_amdgcn_cvt_pk_fp8_f32(v1.z * inv, v1.w * inv, w1, true);
    *(int2*)(out + (size_t)row * DIM + lane * 8) = make_int2(w0, w1);
}

// A = msg_n*10 (fp8), B = img_n (fp8); row-major [8192][512] bytes.
// 128x256 tile, 8 waves (2M x 4N, per-wave 64x64 as 2x2 of 32x32), BK=64.
// LDS per buffer: [rows][4 chunks of 16B], chunk-slot p of row r holds
// logical chunk p ^ ((r>>1)&3); linear GLDS dest, pre-swizzled global src.
// Lane reads logical chunks {2h, 2h+1} (h = lane>>5) of its row — slot
// pattern r*4 + (c^swz) is distinct mod 32 within every 8-lane phase group.
__global__ __launch_bounds__(512, 4) void simloss_mfma(const unsigned char* __restrict__ A,
                                                       const unsigned char* __restrict__ B,
                                                       float* __restrict__ rowsum,
                                                       unsigned* __restrict__ rowmax,
                                                       float* __restrict__ rowpos) {
    __shared__ __attribute__((aligned(16))) unsigned char As[2][BM * BK];  // 2x8 KB
    __shared__ __attribute__((aligned(16))) unsigned char Bs[2][BN * BK];  // 2x16 KB

    const int tid = threadIdx.x;
    const int lane = tid & 63;
    const int r32 = lane & 31;
    const int h = lane >> 5;     // k-half (32 bytes each)
    const int wid = tid >> 6;
    const int wr = wid >> 2;     // 0..1  (M waves)
    const int wc = wid & 3;      // 0..3  (N waves)

    // XCD stripes, bx-major traversal (by fastest): 2048 blocks = 64 by x 32 bx.
    const int bid = blockIdx.x;
    const int xcd = bid & 7;
    const int l = bid >> 3;          // 0..255
    const int by = xcd * 8 + (l & 7);
    const int bx = l >> 3;           // 0..31
    const int rowBase = by * BM;
    const int colBase = bx * BN;

    // staging: thread -> (row = tid>>2, slot = tid&3); fetch logical chunk
    // slot ^ ((row>>1)&3). B rows 128..255: +128 doesn't change bits 1-2.
    const int srow = tid >> 2;
    const int sc = (tid & 3) ^ ((srow >> 1) & 3);
    const unsigned char* gA = A + (size_t)(rowBase + srow) * DIM + sc * 16;
    const unsigned char* gB = B + (size_t)(colBase + srow) * DIM + sc * 16;

#define STAGE(b, koff)                                         \
    do {                                                       \
        GLDS(gA + (koff), &As[b][tid * 16]);                   \
        GLDS(gB + (koff), &Bs[b][tid * 16]);                   \
        GLDS(gB + 128 * DIM + (koff), &Bs[b][8192 + tid * 16]); \
    } while (0)

    // fragment read base (bytes); logical chunks {2h, 2h+1} -> slots ^swz;
    // second chunk's slot = first ^ 1 -> byte addr ^ 16.
    const int swz = (r32 >> 1) & 3;
    const int aAddr = (wr * 64 + r32) * BK + ((((h << 1)) ^ swz) << 4);
    const int bAddr = (wc * 64 + r32) * BK + ((((h << 1)) ^ swz) << 4);

    f32x16 acc[2][2] = {};

#define VMCNT(n) asm volatile("s_waitcnt vmcnt(" #n ")" ::: "memory")
#define BAR() __builtin_amdgcn_s_barrier()

    // prologue: stage tile 0
    STAGE(0, 0);

    for (int t = 0; t < NSTEP; ++t) {
        const int b = t & 1;
        if (t < NSTEP - 1) {
            STAGE(b ^ 1, (t + 1) * BK);  // next tile's 3 GLDS in flight
            VMCNT(3);                    // tile t's 3 GLDS landed
        } else {
            VMCNT(0);
        }
        BAR();
        // A fragments: rows wr*64 + ms*32 + r32, 32 k-bytes (2 x b128)
        uint4 a0l = *(const uint4*)&As[b][aAddr];
        uint4 a0h = *(const uint4*)&As[b][aAddr ^ 16];
        uint4 a1l = *(const uint4*)&As[b][aAddr + 2048];
        uint4 a1h = *(const uint4*)&As[b][(aAddr + 2048) ^ 16];
        uint4 b0l = *(const uint4*)&Bs[b][bAddr];
        uint4 b0h = *(const uint4*)&Bs[b][bAddr ^ 16];
        uint4 b1l = *(const uint4*)&Bs[b][bAddr + 2048];
        uint4 b1h = *(const uint4*)&Bs[b][(bAddr + 2048) ^ 16];
        i32x8 af0 = {(int)a0l.x, (int)a0l.y, (int)a0l.z, (int)a0l.w,
                     (int)a0h.x, (int)a0h.y, (int)a0h.z, (int)a0h.w};
        i32x8 af1 = {(int)a1l.x, (int)a1l.y, (int)a1l.z, (int)a1l.w,
                     (int)a1h.x, (int)a1h.y, (int)a1h.z, (int)a1h.w};
        i32x8 bf0 = {(int)b0l.x, (int)b0l.y, (int)b0l.z, (int)b0l.w,
                     (int)b0h.x, (int)b0h.y, (int)b0h.z, (int)b0h.w};
        i32x8 bf1 = {(int)b1l.x, (int)b1l.y, (int)b1l.z, (int)b1l.w,
                     (int)b1h.x, (int)b1h.y, (int)b1h.z, (int)b1h.w};
        __builtin_amdgcn_s_setprio(1);
        // cbsz=0 (A=e4m3), blgp=0 (B=e4m3); unit e8m0 scales (0x7f = 2^0),
        // uniform bytes -> opsel irrelevant.
        acc[0][0] = __builtin_amdgcn_mfma_scale_f32_32x32x64_f8f6f4(
            af0, bf0, acc[0][0], 0, 0, 0, 0x7f7f7f7f, 0, 0x7f7f7f7f);
        acc[0][1] = __builtin_amdgcn_mfma_scale_f32_32x32x64_f8f6f4(
            af0, bf1, acc[0][1], 0, 0, 0, 0x7f7f7f7f, 0, 0x7f7f7f7f);
        acc[1][0] = __builtin_amdgcn_mfma_scale_f32_32x32x64_f8f6f4(
            af1, bf0, acc[1][0], 0, 0, 0, 0x7f7f7f7f, 0, 0x7f7f7f7f);
        acc[1][1] = __builtin_amdgcn_mfma_scale_f32_32x32x64_f8f6f4(
            af1, bf1, acc[1][1], 0, 0, 0, 0x7f7f7f7f, 0, 0x7f7f7f7f);
        __builtin_amdgcn_s_setprio(0);
        BAR();  // all waves done reading buf b before it is restaged
    }

    // ---- fused epilogue ----
    // 32x32 C/D layout [m74/m101]: col = lane&31, row = (reg&3)+8*(reg>>2)+4*h
    __syncthreads();
    float* ssum = (float*)&As[0][0];  // 128*4 floats
    float* smx = ssum + 512;          // 128*4 floats
    const int baseRow = rowBase + wr * 64 + 4 * h;
    const int baseCol = colBase + wc * 64 + r32;
    #pragma unroll
    for (int ms = 0; ms < 2; ++ms) {
        #pragma unroll
        for (int reg = 0; reg < 16; ++reg) {
            const int i = baseRow + ms * 32 + (reg & 3) + 8 * (reg >> 2);
            const int partner = i ^ BATCHD;
            float sum = 0.f, mx = -1e30f;
            #pragma unroll
            for (int ns = 0; ns < 2; ++ns) {
                const int j = baseCol + ns * 32;
                const float s = acc[ms][ns][reg];
                const bool isDiag = (j == i);
                const bool isPos = (j == partner);
                float e = __expf(s - SHIFT);
                if (isDiag) e = 0.f;
                sum += e;
                if (!isDiag && !isPos) mx = fmaxf(mx, s);
                if (isPos) rowpos[i] = s;  // exactly one writer grid-wide
            }
            // reduce across the 32 lanes of this h-group (cols)
            #pragma unroll
            for (int off = 1; off < 32; off <<= 1) {
                sum += __shfl_xor(sum, off);
                mx = fmaxf(mx, __shfl_xor(mx, off));
            }
            if (r32 == 0) {
                const int rloc = wr * 64 + ms * 32 + (reg & 3) + 8 * (reg >> 2) + 4 * h;
                ssum[rloc * 4 + wc] = sum;
                smx[rloc * 4 + wc] = mx;
            }
        }
    }
    __syncthreads();
    // combine the 4 column-waves' partials: one atomic pair per row per block
    if (tid < BM) {
        const float s = ssum[tid * 4 + 0] + ssum[tid * 4 + 1] +
                        ssum[tid * 4 + 2] + ssum[tid * 4 + 3];
        const float mx = fmaxf(fmaxf(smx[tid * 4 + 0], smx[tid * 4 + 1]),
                               fmaxf(smx[tid * 4 + 2], smx[tid * 4 + 3]));
        const int i = rowBase + tid;
        atomicAdd(&rowsum[i], s);
        atomicMax(&rowmax[i], f2u_ord(mx));
    }
#undef STAGE
#undef VMCNT
#undef BAR
}

// 32 blocks x 256 threads: one row per thread, block-reduce, atomic combine.
__global__ __launch_bounds__(256) void finalize_partial(const float* __restrict__ rowsum,
                                                        const unsigned* __restrict__ rowmax,
                                                        const float* __restrict__ rowpos,
                                                        float* __restrict__ accum) {
    const int tid = threadIdx.x;
    const int i = blockIdx.x * 256 + tid;
    const float lse = SHIFT + logf(rowsum[i]);
    const float pos = rowpos[i];
    float lossAcc = lse - pos;
    float hitAcc = (pos >= u2f_ord(rowmax[i])) ? 1.f : 0.f;
    __shared__ float sl[256], sa[256];
    sl[tid] = lossAcc; sa[tid] = hitAcc;
    __syncthreads();
    for (int s = 128; s > 0; s >>= 1) {
        if (tid < s) { sl[tid] += sl[tid + s]; sa[tid] += sa[tid + s]; }
        __syncthreads();
    }
    if (tid == 0) {
        atomicAdd(&accum[0], sl[0]);
        atomicAdd(&accum[1], sa[0]);
    }
}

__global__ void finalize_write(const float* __restrict__ accum, float* __restrict__ out) {
    if (threadIdx.x == 0) {
        out[0] = accum[0] / (float)NROWS;
        out[1] = accum[1] / (float)NROWS;
    }
}

extern "C" void kernel_launch(void* const* d_in, const int* in_sizes, int n_in,
                              void* d_out, int out_size, void* d_ws, size_t ws_size,
                              hipStream_t stream) {
    const float* msg = (const float*)d_in[0];
    const float* img = (const float*)d_in[1];
    float* out = (float*)d_out;

    char* ws = (char*)d_ws;
    const size_t matBytes = (size_t)NROWS * DIM;  // 4 MB (fp8)
    unsigned char* mnb = (unsigned char*)ws;
    unsigned char* imb = (unsigned char*)(ws + matBytes);
    float* rowsum = (float*)(ws + 2 * matBytes);
    unsigned* rowmax = (unsigned*)(ws + 2 * matBytes + NROWS * sizeof(float));
    float* rowpos = (float*)(ws + 2 * matBytes + 2 * NROWS * sizeof(float));
    float* accum = (float*)(ws + 2 * matBytes + 3 * NROWS * sizeof(float));

    normalize_fp8_both<<<2 * NROWS, 64, 0, stream>>>(msg, img, mnb, imb,
                                                     rowsum, rowmax, accum);

    simloss_mfma<<<(NROWS / BM) * (NROWS / BN), 512, 0, stream>>>(mnb, imb, rowsum,
                                                                  rowmax, rowpos);

    finalize_partial<<<NROWS / 256, 256, 0, stream>>>(rowsum, rowmax, rowpos, accum);
    finalize_write<<<1, 64, 0, stream>>>(accum, out);
}

// Round 9
// 110.650 us; speedup vs baseline: 2.0100x; 2.0100x over previous
//
#include <hip/hip_runtime.h>
#include <hip/hip_bf16.h>

// NT-Xent, BATCH=4096, N=8192, D=512, TEMP=0.1 — MX-fp8 (e4m3, unit scales)
// mfma_scale_f32_32x32x64_f8f6f4. Round 9: 128x128 tile, BK=64, 512 thr,
// per-wave 32x64 (acc 32 regs -> no spill), 32 KB LDS, 2 blocks/CU.
// loss = mean_i [ logsumexp_{j!=i} sim[i,j] - sim[i,partner(i)] ]
// acc  = mean_i [ sim[i,partner(i)] >= max_{j!=i,partner} sim[i,j] ]
// sim = (msg_n . img_n^T)/TEMP, 10x folded into msg side before fp8 cast.

#define NROWS 8192
#define BATCHD 4096
#define DIM 512
#define BM 128
#define BN 128
#define BK 64
#define NSTEP (DIM / BK)   // 8 K-steps
#define SHIFT 10.0f

typedef int i32x8 __attribute__((ext_vector_type(8)));
typedef float f32x16 __attribute__((ext_vector_type(16)));

#define GLDS(g, l)                                                             \
    __builtin_amdgcn_global_load_lds(                                          \
        (const __attribute__((address_space(1))) void*)(g),                    \
        (__attribute__((address_space(3))) void*)(l), 16, 0, 0)

__device__ __forceinline__ unsigned f2u_ord(float f) {
    unsigned u = __float_as_uint(f);
    return (u & 0x80000000u) ? ~u : (u | 0x80000000u);
}
__device__ __forceinline__ float u2f_ord(unsigned e) {
    return (e & 0x80000000u) ? __uint_as_float(e & 0x7fffffffu) : __uint_as_float(~e);
}

// blocks 0..NROWS-1: msg (x10); NROWS..2*NROWS-1: img (x1).
// First 128 blocks also zero rowsum/rowmax/accum.
__global__ __launch_bounds__(64) void normalize_fp8_both(const float* __restrict__ msg,
                                                         const float* __restrict__ img,
                                                         unsigned char* __restrict__ mnb,
                                                         unsigned char* __restrict__ imb,
                                                         float* __restrict__ rowsum,
                                                         unsigned* __restrict__ rowmax,
                                                         float* __restrict__ accum) {
    if (blockIdx.x < 128) {
        const int i = blockIdx.x * 64 + threadIdx.x;
        rowsum[i] = 0.f;
        rowmax[i] = 0u;  // encodes "most negative"
        if (i < 2) accum[i] = 0.f;
    }
    int row = blockIdx.x;
    const float* in;
    unsigned char* out;
    float scale;
    if (row < NROWS) { in = msg; out = mnb; scale = 10.0f; }
    else { row -= NROWS; in = img; out = imb; scale = 1.0f; }
    const int lane = threadIdx.x;
    const float* src = in + (size_t)row * DIM + lane * 8;
    float4 v0 = *(const float4*)(src);
    float4 v1 = *(const float4*)(src + 4);
    float ss = v0.x*v0.x + v0.y*v0.y + v0.z*v0.z + v0.w*v0.w
             + v1.x*v1.x + v1.y*v1.y + v1.z*v1.z + v1.w*v1.w;
    #pragma unroll
    for (int off = 1; off < 64; off <<= 1) ss += __shfl_xor(ss, off);
    const float inv = scale / fmaxf(sqrtf(ss), 1e-8f);
    int w0 = __builtin_amdgcn_cvt_pk_fp8_f32(v0.x * inv, v0.y * inv, 0, false);
    w0 = __builtin_amdgcn_cvt_pk_fp8_f32(v0.z * inv, v0.w * inv, w0, true);
    int w1 = __builtin_amdgcn_cvt_pk_fp8_f32(v1.x * inv, v1.y * inv, 0, false);
    w1 = __builtin_amdgcn_cvt_pk_fp8_f32(v1.z * inv, v1.w * inv, w1, true);
    *(int2*)(out + (size_t)row * DIM + lane * 8) = make_int2(w0, w1);
}

// A = msg_n*10 (fp8), B = img_n (fp8); row-major [8192][512] bytes.
// 128x128 tile, 8 waves (4M x 2N, per-wave 32x64 as 1x2 of 32x32), BK=64.
// LDS per buffer: [128 rows][4 chunks of 16B], chunk-slot p of row r holds
// logical chunk p ^ ((r>>1)&3); linear GLDS dest, pre-swizzled global src.
__global__ __launch_bounds__(512, 4) void simloss_mfma(const unsigned char* __restrict__ A,
                                                       const unsigned char* __restrict__ B,
                                                       float* __restrict__ rowsum,
                                                       unsigned* __restrict__ rowmax,
                                                       float* __restrict__ rowpos) {
    __shared__ __attribute__((aligned(16))) unsigned char As[2][BM * BK];  // 2x8 KB
    __shared__ __attribute__((aligned(16))) unsigned char Bs[2][BN * BK];  // 2x8 KB

    const int tid = threadIdx.x;
    const int lane = tid & 63;
    const int r32 = lane & 31;
    const int h = lane >> 5;     // k-half (32 bytes each)
    const int wid = tid >> 6;
    const int wr = wid >> 1;     // 0..3  (M waves, 32 rows each)
    const int wc = wid & 1;      // 0..1  (N waves, 64 cols each)

    // XCD stripes, bx-major traversal (by fastest): 4096 blocks = 64 by x 64 bx.
    const int bid = blockIdx.x;
    const int xcd = bid & 7;
    const int l = bid >> 3;          // 0..511
    const int by = xcd * 8 + (l & 7);
    const int bx = l >> 3;           // 0..63
    const int rowBase = by * BM;
    const int colBase = bx * BN;

    // staging: thread -> (row = tid>>2, slot = tid&3); fetch logical chunk
    // slot ^ ((row>>1)&3)  [inverse of read swizzle].
    const int srow = tid >> 2;
    const int sc = (tid & 3) ^ ((srow >> 1) & 3);
    const unsigned char* gA = A + (size_t)(rowBase + srow) * DIM + sc * 16;
    const unsigned char* gB = B + (size_t)(colBase + srow) * DIM + sc * 16;

#define STAGE(b, koff)                          \
    do {                                        \
        GLDS(gA + (koff), &As[b][tid * 16]);    \
        GLDS(gB + (koff), &Bs[b][tid * 16]);    \
    } while (0)

    // fragment read base (bytes): lane reads logical chunks {2h, 2h+1} of its
    // row; slot = chunk ^ swz; second chunk's slot = first ^ 1 -> addr ^ 16.
    const int swz = (r32 >> 1) & 3;
    const int aAddr = (wr * 32 + r32) * BK + (((h << 1) ^ swz) << 4);
    const int bAddr = (wc * 64 + r32) * BK + (((h << 1) ^ swz) << 4);

    f32x16 acc0 = {}, acc1 = {};

#define VMCNT(n) asm volatile("s_waitcnt vmcnt(" #n ")" ::: "memory")
#define BAR() __builtin_amdgcn_s_barrier()

    // prologue: stage tile 0
    STAGE(0, 0);

    for (int t = 0; t < NSTEP; ++t) {
        const int b = t & 1;
        if (t < NSTEP - 1) {
            STAGE(b ^ 1, (t + 1) * BK);  // next tile's 2 GLDS in flight
            VMCNT(2);                    // tile t's 2 GLDS landed
        } else {
            VMCNT(0);
        }
        BAR();
        i32x8 af, bf0, bf1;
        *(uint4*)&af = *(const uint4*)&As[b][aAddr];
        *((uint4*)&af + 1) = *(const uint4*)&As[b][aAddr ^ 16];
        *(uint4*)&bf0 = *(const uint4*)&Bs[b][bAddr];
        *((uint4*)&bf0 + 1) = *(const uint4*)&Bs[b][bAddr ^ 16];
        *(uint4*)&bf1 = *(const uint4*)&Bs[b][bAddr + 2048];
        *((uint4*)&bf1 + 1) = *(const uint4*)&Bs[b][(bAddr + 2048) ^ 16];
        __builtin_amdgcn_s_setprio(1);
        // cbsz=0 (A=e4m3), blgp=0 (B=e4m3); unit e8m0 scales (0x7f = 2^0).
        acc0 = __builtin_amdgcn_mfma_scale_f32_32x32x64_f8f6f4(
            af, bf0, acc0, 0, 0, 0, 0x7f7f7f7f, 0, 0x7f7f7f7f);
        acc1 = __builtin_amdgcn_mfma_scale_f32_32x32x64_f8f6f4(
            af, bf1, acc1, 0, 0, 0, 0x7f7f7f7f, 0, 0x7f7f7f7f);
        __builtin_amdgcn_s_setprio(0);
        BAR();  // all waves done reading buf b before it is restaged
    }

    // ---- fused epilogue ----
    // 32x32 C/D layout [m74/m101]: col = lane&31, row = (reg&3)+8*(reg>>2)+4*h
    __syncthreads();
    float* ssum = (float*)&As[0][0];  // 128*2 floats
    float* smx = ssum + 256;          // 128*2 floats
    const int baseRow = rowBase + wr * 32 + 4 * h;
    const int baseCol = colBase + wc * 64 + r32;
    #pragma unroll
    for (int reg = 0; reg < 16; ++reg) {
        const int rloc0 = (reg & 3) + 8 * (reg >> 2);
        const int i = baseRow + rloc0;
        const int partner = i ^ BATCHD;
        float sum = 0.f, mx = -1e30f;
        #pragma unroll
        for (int ns = 0; ns < 2; ++ns) {
            const int j = baseCol + ns * 32;
            const float s = (ns == 0) ? acc0[reg] : acc1[reg];
            const bool isDiag = (j == i);
            const bool isPos = (j == partner);
            float e = __expf(s - SHIFT);
            if (isDiag) e = 0.f;
            sum += e;
            if (!isDiag && !isPos) mx = fmaxf(mx, s);
            if (isPos) rowpos[i] = s;  // exactly one writer grid-wide
        }
        // reduce across the 32 lanes (cols) of this h-group
        #pragma unroll
        for (int off = 1; off < 32; off <<= 1) {
            sum += __shfl_xor(sum, off);
            mx = fmaxf(mx, __shfl_xor(mx, off));
        }
        if (r32 == 0) {
            const int rloc = wr * 32 + rloc0 + 4 * h;
            ssum[rloc * 2 + wc] = sum;
            smx[rloc * 2 + wc] = mx;
        }
    }
    __syncthreads();
    // combine the 2 column-waves' partials: one atomic pair per row per block
    if (tid < BM) {
        const float s = ssum[tid * 2 + 0] + ssum[tid * 2 + 1];
        const float mx = fmaxf(smx[tid * 2 + 0], smx[tid * 2 + 1]);
        const int i = rowBase + tid;
        atomicAdd(&rowsum[i], s);
        atomicMax(&rowmax[i], f2u_ord(mx));
    }
#undef STAGE
#undef VMCNT
#undef BAR
}

// 32 blocks x 256 threads: one row per thread, block-reduce, atomic combine.
__global__ __launch_bounds__(256) void finalize_partial(const float* __restrict__ rowsum,
                                                        const unsigned* __restrict__ rowmax,
                                                        const float* __restrict__ rowpos,
                                                        float* __restrict__ accum) {
    const int tid = threadIdx.x;
    const int i = blockIdx.x * 256 + tid;
    const float lse = SHIFT + logf(rowsum[i]);
    const float pos = rowpos[i];
    float lossAcc = lse - pos;
    float hitAcc = (pos >= u2f_ord(rowmax[i])) ? 1.f : 0.f;
    __shared__ float sl[256], sa[256];
    sl[tid] = lossAcc; sa[tid] = hitAcc;
    __syncthreads();
    for (int s = 128; s > 0; s >>= 1) {
        if (tid < s) { sl[tid] += sl[tid + s]; sa[tid] += sa[tid + s]; }
        __syncthreads();
    }
    if (tid == 0) {
        atomicAdd(&accum[0], sl[0]);
        atomicAdd(&accum[1], sa[0]);
    }
}

__global__ void finalize_write(const float* __restrict__ accum, float* __restrict__ out) {
    if (threadIdx.x == 0) {
        out[0] = accum[0] / (float)NROWS;
        out[1] = accum[1] / (float)NROWS;
    }
}

extern "C" void kernel_launch(void* const* d_in, const int* in_sizes, int n_in,
                              void* d_out, int out_size, void* d_ws, size_t ws_size,
                              hipStream_t stream) {
    const float* msg = (const float*)d_in[0];
    const float* img = (const float*)d_in[1];
    float* out = (float*)d_out;

    char* ws = (char*)d_ws;
    const size_t matBytes = (size_t)NROWS * DIM;  // 4 MB (fp8)
    unsigned char* mnb = (unsigned char*)ws;
    unsigned char* imb = (unsigned char*)(ws + matBytes);
    float* rowsum = (float*)(ws + 2 * matBytes);
    unsigned* rowmax = (unsigned*)(ws + 2 * matBytes + NROWS * sizeof(float));
    float* rowpos = (float*)(ws + 2 * matBytes + 2 * NROWS * sizeof(float));
    float* accum = (float*)(ws + 2 * matBytes + 3 * NROWS * sizeof(float));

    normalize_fp8_both<<<2 * NROWS, 64, 0, stream>>>(msg, img, mnb, imb,
                                                     rowsum, rowmax, accum);

    simloss_mfma<<<(NROWS / BM) * (NROWS / BN), 512, 0, stream>>>(mnb, imb, rowsum,
                                                                  rowmax, rowpos);

    finalize_partial<<<NROWS / 256, 256, 0, stream>>>(rowsum, rowmax, rowpos, accum);
    finalize_write<<<1, 64, 0, stream>>>(accum, out);
}